// Round 9
// baseline (330.676 us; speedup 1.0000x reference)
//
#include <hip/hip_runtime.h>
#include <math.h>

// RWKV single-token forward — ONE persistent kernel, overlap-preserving sync.
// Base = round-4 (242us) work split + flag barrier. Changes:
//  - NO __syncthreads in the layer loop: all intra-phase syncs are
//    lgkmcnt-only raw s_barrier (LDS ordering), so in-flight weight bursts
//    are never drained by a barrier.
//  - Cross-block gathers are relaxed agent-scope atomic loads (compiler emits
//    COUNTED vmcnt waits). Each body issues gather FIRST, then the next
//    phase's weight burst -> the burst is younger than the gather and is
//    never drained by the gather wait; it streams across the whole cycle.
//  - Only wave 0 publishes + flags: publish -> vmcnt(0) (its queue is empty,
//    its weight burst is issued AFTER the flag) -> flag -> own burst -> poll
//    all 256 flags (4 per lane, 128B stride) -> s_barrier releases the block.
//  - P3's km goes through LDS so wave 0 is the sole publisher.

typedef unsigned long long u64;
typedef unsigned u32;

constexpr int E = 1024;
constexpr int H = 4096;
constexpr int V = 50277;
constexpr int L = 12;
constexpr int NBLK = 256;
constexpr int NTHR = 512;
constexpr float LN_EPS = 9.999999747378752e-06f;

#define SA __HIP_MEMORY_SCOPE_AGENT

__device__ __forceinline__ void stf(float *p, float v) {
  __hip_atomic_store(p, v, __ATOMIC_RELAXED, SA);
}
__device__ __forceinline__ void stu(u32 *p, u32 v) {
  __hip_atomic_store(p, v, __ATOMIC_RELAXED, SA);
}
__device__ __forceinline__ u32 ldu(const u32 *p) {
  return __hip_atomic_load(p, __ATOMIC_RELAXED, SA);
}
__device__ __forceinline__ float2 ld2(const float *p) {
  union { u64 u; float2 f; } c;
  c.u = __hip_atomic_load((const u64 *)p, __ATOMIC_RELAXED, SA);
  return c.f;
}

// LDS-only barrier: never drains vmem.
__device__ __forceinline__ void lds_sync() {
  asm volatile("s_waitcnt lgkmcnt(0)" ::: "memory");
  __builtin_amdgcn_s_barrier();
}
__device__ __forceinline__ void vdrain() {
  asm volatile("s_waitcnt vmcnt(0)" ::: "memory");
}

struct Args {
  const float *statea, *stateb, *statec, *stated, *pre;
  const float *ln1w, *ln1b, *ln2w, *ln2b;
  const float *ak, *ar, *av, *kk, *vv, *rr, *tf, *td, *ovv;
  const float *tmk, *tmr, *kf, *rf, *vf;
  const float *post0, *post1, *post2;
  const int *token;
  float *out;
  u32 *flags;                    // 256 flags, stride 32 dwords (128 B)
  float *wu, *wsx, *wx, *wkm;    // coherent cross-block vectors
};

__device__ __forceinline__ float wred(float v) {
#pragma unroll
  for (int off = 32; off; off >>= 1) v += __shfl_down(v, off, 64);
  return v;
}
__device__ __forceinline__ float dot4(float4 w, float4 x) {
  return w.x * x.x + w.y * x.y + w.z * x.z + w.w * x.w;
}

// ---- weight bundle loads (issued one phase ahead) ----
struct P1B {
  float4 w[6];
  float2 lw, lb, sa, kk, vv, rr;
  float tf, td, sb, sc;
};
__device__ __forceinline__ void load_p1(P1B &p, const Args &a, int l, int grow,
                                        int b0h, int tid, int blk) {
  const size_t lE = (size_t)l * E;
  const float4 *kr = reinterpret_cast<const float4 *>(a.ak + (lE + grow) * E);
  const float4 *vr = reinterpret_cast<const float4 *>(a.av + (lE + grow) * E);
  const float4 *rr4 = reinterpret_cast<const float4 *>(a.ar + (lE + grow) * E);
  p.w[0] = kr[b0h]; p.w[1] = kr[b0h + 64];
  p.w[2] = vr[b0h]; p.w[3] = vr[b0h + 64];
  p.w[4] = rr4[b0h]; p.w[5] = rr4[b0h + 64];
  p.lw = reinterpret_cast<const float2 *>(a.ln1w + lE)[tid];
  p.lb = reinterpret_cast<const float2 *>(a.ln1b + lE)[tid];
  p.sa = reinterpret_cast<const float2 *>(a.statea + lE)[tid];
  p.kk = reinterpret_cast<const float2 *>(a.kk + lE)[tid];
  p.vv = reinterpret_cast<const float2 *>(a.vv + lE)[tid];
  p.rr = reinterpret_cast<const float2 *>(a.rr + lE)[tid];
  if (tid < 4) {
    size_t o = lE + blk * 4 + tid;
    p.tf = a.tf[o]; p.td = a.td[o]; p.sb = a.stateb[o]; p.sc = a.statec[o];
  } else {
    p.tf = 0.f; p.td = 0.f; p.sb = 0.f; p.sc = 1.f;
  }
}
__device__ __forceinline__ void load_ovv_kf0(float4 po[2], float4 pf[8],
                                             const Args &a, int l, int grow,
                                             int b0h, int blk, int wid, int lane) {
  const size_t lE = (size_t)l * E;
  const float4 *orow = reinterpret_cast<const float4 *>(a.ovv + (lE + grow) * E);
  po[0] = orow[b0h]; po[1] = orow[b0h + 64];
  const float *kfb = a.kf + (size_t)l * H * E;
  const float4 *k0 = reinterpret_cast<const float4 *>(kfb + (size_t)(blk * 16 + wid) * E);
  pf[0] = k0[lane]; pf[1] = k0[lane + 64]; pf[2] = k0[lane + 128]; pf[3] = k0[lane + 192];
}
struct P3B {
  float4 r[2];
  float2 lw, lb, sd, tk, tr;
};
__device__ __forceinline__ void load_kf1_rf(float4 pf[8], P3B &p, const Args &a,
                                            int l, int grow, int b0h, int blk,
                                            int wid, int lane, int tid) {
  const size_t lE = (size_t)l * E;
  const float *kfb = a.kf + (size_t)l * H * E;
  const float4 *k1 = reinterpret_cast<const float4 *>(kfb + (size_t)(blk * 16 + 8 + wid) * E);
  pf[4] = k1[lane]; pf[5] = k1[lane + 64]; pf[6] = k1[lane + 128]; pf[7] = k1[lane + 192];
  const float4 *rrow = reinterpret_cast<const float4 *>(a.rf + (lE + grow) * E);
  p.r[0] = rrow[b0h]; p.r[1] = rrow[b0h + 64];
  p.lw = reinterpret_cast<const float2 *>(a.ln2w + lE)[tid];
  p.lb = reinterpret_cast<const float2 *>(a.ln2b + lE)[tid];
  p.sd = reinterpret_cast<const float2 *>(a.stated + lE)[tid];
  p.tk = reinterpret_cast<const float2 *>(a.tmk + lE)[tid];
  p.tr = reinterpret_cast<const float2 *>(a.tmr + lE)[tid];
}
__device__ __forceinline__ void load_vf(float4 pv[8], const Args &a, int l,
                                        int grow, int bv) {
  const float4 *vrow = reinterpret_cast<const float4 *>(a.vf + ((size_t)l * E + grow) * H);
  pv[0] = vrow[bv];       pv[1] = vrow[bv + 64];
  pv[2] = vrow[bv + 128]; pv[3] = vrow[bv + 192];
  pv[4] = vrow[bv + 256]; pv[5] = vrow[bv + 320];
  pv[6] = vrow[bv + 384]; pv[7] = vrow[bv + 448];
}

// wave-0: poll all 256 flags (4 per lane, 128B stride)
__device__ __forceinline__ void poll_flags(const u32 *flags, unsigned ep, int lane) {
  const u32 *f0 = flags + (lane * 4 + 0) * 32;
  const u32 *f1 = flags + (lane * 4 + 1) * 32;
  const u32 *f2 = flags + (lane * 4 + 2) * 32;
  const u32 *f3 = flags + (lane * 4 + 3) * 32;
  for (;;) {
    u32 a0 = ldu(f0), a1 = ldu(f1), a2 = ldu(f2), a3 = ldu(f3);
    if (a0 >= ep && a1 >= ep && a2 >= ep && a3 >= ep) break;
    __builtin_amdgcn_s_sleep(1);
  }
}

__device__ __forceinline__ void loadrow(float4 *d, const float4 *P, int r, int lane) {
  const float4 *p = P + (size_t)r * 256;
  d[0] = p[lane]; d[1] = p[lane + 64]; d[2] = p[lane + 128]; d[3] = p[lane + 192];
}

__global__ __launch_bounds__(NTHR, 2) void rwkv_fused(Args a) {
  __shared__ __align__(16) float s_a[4096];
  __shared__ __align__(16) float s_x[1024];
  __shared__ float s_red[16];
  __shared__ float s_pp[24];
  __shared__ float s_rt[4];

  const int tid = threadIdx.x;
  const int lane = tid & 63;
  const int wid = tid >> 6;        // 0..7
  const int blk = blockIdx.x;
  const int rloc = wid >> 1;
  const int h = wid & 1;
  const int grow = blk * 4 + rloc;
  const int b0h = h * 128 + lane;
  const int bv = h * 512 + lane;

  float *out_logits = a.out;
  float *out_aaa = a.out + V;
  float *out_bbb = out_aaa + L * E;
  float *out_ccc = out_bbb + L * E;
  float *out_ddd = out_ccc + L * E;

  const int tok = a.token[0];
  const float *pre_row = a.pre + (size_t)tok * E;
  const float4 *s4a = reinterpret_cast<const float4 *>(s_a);

  P1B p1;
  float4 po[2], pf[8], pv[8];
  P3B p3;
  unsigned ep = 1;

  load_p1(p1, a, 0, grow, b0h, tid, blk);

#pragma unroll 1
  for (int l = 0; l < L; ++l) {
    const size_t lE = (size_t)l * E;

    // ================= P1: LN1 + k/v/r matvecs + wkv =================
    {
      // gather FIRST (oldest), then burst (younger, never drained by gather wait)
      float2 xv;
      if (l == 0) xv = reinterpret_cast<const float2 *>(pre_row)[tid];
      else        xv = ld2(a.wx + 2 * tid);
      if (wid != 0) load_ovv_kf0(po, pf, a, l, grow, b0h, blk, wid, lane);
      // stats (waits gather via counted vmcnt; burst stays in flight)
      reinterpret_cast<float2 *>(s_x)[tid] = xv;
      float s = xv.x + xv.y, s2 = xv.x * xv.x + xv.y * xv.y;
#pragma unroll
      for (int m = 1; m <= 32; m <<= 1) {
        s += __shfl_xor(s, m, 64);
        s2 += __shfl_xor(s2, m, 64);
      }
      if (lane == 0) { s_red[wid * 2] = s; s_red[wid * 2 + 1] = s2; }
      lds_sync();
      float ts = 0.f, ts2 = 0.f;
#pragma unroll
      for (int i = 0; i < 8; ++i) { ts += s_red[2 * i]; ts2 += s_red[2 * i + 1]; }
      float mn = ts * (1.0f / E);
      float rstd = rsqrtf(ts2 * (1.0f / E) - mn * mn + LN_EPS);
      float2 xy = make_float2((xv.x - mn) * rstd * p1.lw.x + p1.lb.x,
                              (xv.y - mn) * rstd * p1.lw.y + p1.lb.y);
      if ((tid >> 1) == blk) {
        out_aaa[lE + 2 * tid] = xy.x;
        out_aaa[lE + 2 * tid + 1] = xy.y;
      }
      reinterpret_cast<float2 *>(s_a)[tid] =
          make_float2(xy.x + p1.kk.x * p1.sa.x, xy.y + p1.kk.y * p1.sa.y);
      reinterpret_cast<float2 *>(s_a + 1024)[tid] =
          make_float2(xy.x + p1.vv.x * p1.sa.x, xy.y + p1.vv.y * p1.sa.y);
      reinterpret_cast<float2 *>(s_a + 2048)[tid] =
          make_float2(xy.x + p1.rr.x * p1.sa.x, xy.y + p1.rr.y * p1.sa.y);
      lds_sync();
      float accK = dot4(p1.w[0], s4a[b0h]) + dot4(p1.w[1], s4a[b0h + 64]);
      float accV = dot4(p1.w[2], s4a[256 + b0h]) + dot4(p1.w[3], s4a[256 + b0h + 64]);
      float accR = dot4(p1.w[4], s4a[512 + b0h]) + dot4(p1.w[5], s4a[512 + b0h + 64]);
      accK = wred(accK); accV = wred(accV); accR = wred(accR);
      if (lane == 0) {
        s_pp[wid * 3 + 0] = accK;
        s_pp[wid * 3 + 1] = accV;
        s_pp[wid * 3 + 2] = accR;
      }
      lds_sync();
      if (wid == 0) {
        int i = lane & 3;
        float K = s_pp[(2 * i) * 3] + s_pp[(2 * i + 1) * 3];
        float Vv = s_pp[(2 * i) * 3 + 1] + s_pp[(2 * i + 1) * 3 + 1];
        float R = s_pp[(2 * i) * 3 + 2] + s_pp[(2 * i + 1) * 3 + 2];
        if (lane < 4) {
          size_t o = lE + blk * 4 + lane;
          float kx = expf(K), rx = expf(R) + 1.0f;
          float etf = expf(p1.tf), etd = expf(p1.td);
          float w_ = p1.sb + etf * kx * Vv;
          float d_ = p1.sc * rx + etf * kx * rx;
          stf(a.wu + blk * 4 + lane, w_ / (d_ + 0.001f));
          out_bbb[o] = p1.sb * etd + kx * Vv;
          out_ccc[o] = p1.sc * etd + kx;
        }
        vdrain();
        if (lane == 0) stu(a.flags + blk * 32, ep);
        load_ovv_kf0(po, pf, a, l, grow, b0h, blk, wid, lane);
        poll_flags(a.flags, ep, lane);
      }
      lds_sync(); ++ep;
    }

    // ================= P2: sxx = x + ovv @ u =================
    {
      float2 u2 = ld2(a.wu + 2 * tid);
      if (wid != 0) load_kf1_rf(pf, p3, a, l, grow, b0h, blk, wid, lane, tid);
      reinterpret_cast<float2 *>(s_a)[tid] = u2;
      lds_sync();
      float acc = dot4(po[0], s4a[b0h]) + dot4(po[1], s4a[b0h + 64]);
      acc = wred(acc);
      if (lane == 0) s_pp[wid] = acc;
      lds_sync();
      if (wid == 0) {
        int i = lane & 3;
        float sxx = s_x[blk * 4 + i] + s_pp[2 * i] + s_pp[2 * i + 1];
        if (lane < 4) stf(a.wsx + blk * 4 + lane, sxx);
        vdrain();
        if (lane == 0) stu(a.flags + blk * 32, ep);
        load_kf1_rf(pf, p3, a, l, grow, b0h, blk, wid, lane, tid);
        poll_flags(a.flags, ep, lane);
      }
      lds_sync(); ++ep;
    }

    // ================= P3: LN2 + key_ffn + receptance_ffn =================
    {
      float2 sxv = ld2(a.wsx + 2 * tid);
      if (wid != 0) load_vf(pv, a, l, grow, bv);
      reinterpret_cast<float2 *>(s_x)[tid] = sxv;
      float s = sxv.x + sxv.y, s2 = sxv.x * sxv.x + sxv.y * sxv.y;
#pragma unroll
      for (int m = 1; m <= 32; m <<= 1) {
        s += __shfl_xor(s, m, 64);
        s2 += __shfl_xor(s2, m, 64);
      }
      if (lane == 0) { s_red[wid * 2] = s; s_red[wid * 2 + 1] = s2; }
      lds_sync();
      float ts = 0.f, ts2 = 0.f;
#pragma unroll
      for (int i = 0; i < 8; ++i) { ts += s_red[2 * i]; ts2 += s_red[2 * i + 1]; }
      float mn = ts * (1.0f / E);
      float rstd = rsqrtf(ts2 * (1.0f / E) - mn * mn + LN_EPS);
      float2 xx = make_float2((sxv.x - mn) * rstd * p3.lw.x + p3.lb.x,
                              (sxv.y - mn) * rstd * p3.lw.y + p3.lb.y);
      if ((tid >> 1) == blk) {
        out_ddd[lE + 2 * tid] = xx.x;
        out_ddd[lE + 2 * tid + 1] = xx.y;
      }
      reinterpret_cast<float2 *>(s_a)[tid] =
          make_float2(xx.x + p3.tk.x * p3.sd.x, xx.y + p3.tk.y * p3.sd.y);
      reinterpret_cast<float2 *>(s_a + 1024)[tid] =
          make_float2(xx.x + p3.tr.x * p3.sd.x, xx.y + p3.tr.y * p3.sd.y);
      lds_sync();
      float k0 = 0.f, k1 = 0.f;
#pragma unroll
      for (int it = 0; it < 4; ++it) {
        float4 xv4 = s4a[it * 64 + lane];
        k0 += dot4(pf[it], xv4);
        k1 += dot4(pf[4 + it], xv4);
      }
      float ar_ = dot4(p3.r[0], s4a[256 + b0h]) + dot4(p3.r[1], s4a[256 + b0h + 64]);
      k0 = wred(k0); k1 = wred(k1); ar_ = wred(ar_);
      if (lane == 0) {
        s_pp[wid * 3 + 0] = k0;
        s_pp[wid * 3 + 1] = k1;
        s_pp[wid * 3 + 2] = ar_;
      }
      lds_sync();
      if (wid == 0) {
        if (lane < 4) {
          float arsum = s_pp[(2 * lane) * 3 + 2] + s_pp[(2 * lane + 1) * 3 + 2];
          s_rt[lane] = expf(arsum) + 1.0f;
        }
        if (lane < 16) {
          int w = lane & 7, sel = (lane >> 3) & 1;
          float kv = s_pp[w * 3 + sel];
          float t = fmaxf(kv, 0.f);
          stf(a.wkm + blk * 16 + sel * 8 + w, t * t);
        }
        vdrain();
        if (lane == 0) stu(a.flags + blk * 32, ep);
        load_vf(pv, a, l, grow, bv);
        poll_flags(a.flags, ep, lane);
      }
      lds_sync(); ++ep;
    }

    // ================= P4: x_next = sxx + (vf @ km) / rt =================
    {
      const u64 *km64 = reinterpret_cast<const u64 *>(a.wkm);
      union { u64 u; float2 f; } g0, g1, g2, g3;
      g0.u = __hip_atomic_load(km64 + 2 * tid, __ATOMIC_RELAXED, SA);
      g1.u = __hip_atomic_load(km64 + 2 * tid + 1, __ATOMIC_RELAXED, SA);
      g2.u = __hip_atomic_load(km64 + 1024 + 2 * tid, __ATOMIC_RELAXED, SA);
      g3.u = __hip_atomic_load(km64 + 1024 + 2 * tid + 1, __ATOMIC_RELAXED, SA);
      if (wid != 0) {
        if (l + 1 < L) {
          load_p1(p1, a, l + 1, grow, b0h, tid, blk);
        } else {
          p1.lw = reinterpret_cast<const float2 *>(a.post0)[tid];
          p1.lb = reinterpret_cast<const float2 *>(a.post1)[tid];
        }
      }
      reinterpret_cast<float2 *>(s_a)[2 * tid] = g0.f;
      reinterpret_cast<float2 *>(s_a)[2 * tid + 1] = g1.f;
      reinterpret_cast<float2 *>(s_a)[1024 + 2 * tid] = g2.f;
      reinterpret_cast<float2 *>(s_a)[1024 + 2 * tid + 1] = g3.f;
      lds_sync();
      float acc = 0.f;
#pragma unroll
      for (int it = 0; it < 8; ++it) acc += dot4(pv[it], s4a[bv + it * 64]);
      acc = wred(acc);
      if (lane == 0) s_pp[wid] = acc;
      lds_sync();
      if (wid == 0) {
        int i = lane & 3;
        float xn = s_x[blk * 4 + i] + (s_pp[2 * i] + s_pp[2 * i + 1]) / s_rt[i];
        if (lane < 4) stf(a.wx + blk * 4 + lane, xn);
        vdrain();
        if (lane == 0) stu(a.flags + blk * 32, ep);
        if (l + 1 < L) {
          load_p1(p1, a, l + 1, grow, b0h, tid, blk);
        } else {
          p1.lw = reinterpret_cast<const float2 *>(a.post0)[tid];
          p1.lb = reinterpret_cast<const float2 *>(a.post1)[tid];
        }
        poll_flags(a.flags, ep, lane);
      }
      lds_sync(); ++ep;
    }
  }

  // ================= Final: LN + logits (double-buffered) =================
  {
    float2 xv = ld2(a.wx + 2 * tid);
    reinterpret_cast<float2 *>(s_x)[tid] = xv;
    float s = xv.x + xv.y, s2 = xv.x * xv.x + xv.y * xv.y;
#pragma unroll
    for (int m = 1; m <= 32; m <<= 1) {
      s += __shfl_xor(s, m, 64);
      s2 += __shfl_xor(s2, m, 64);
    }
    if (lane == 0) { s_red[wid * 2] = s; s_red[wid * 2 + 1] = s2; }
    lds_sync();
    float ts = 0.f, ts2 = 0.f;
#pragma unroll
    for (int i = 0; i < 8; ++i) { ts += s_red[2 * i]; ts2 += s_red[2 * i + 1]; }
    float mn = ts * (1.0f / E);
    float rstd = rsqrtf(ts2 * (1.0f / E) - mn * mn + LN_EPS);
    reinterpret_cast<float2 *>(s_a)[tid] =
        make_float2((xv.x - mn) * rstd * p1.lw.x + p1.lb.x,
                    (xv.y - mn) * rstd * p1.lw.y + p1.lb.y);
    lds_sync();

    const float4 *P2 = reinterpret_cast<const float4 *>(a.post2);
    const int gw = blk * 8 + wid;  // 0..2047
    int r0 = gw, r1 = gw + 2048;
    float4 A0[4], A1[4];
    loadrow(A0, P2, r0, lane);
    loadrow(A1, P2, r1 < V ? r1 : r0, lane);
    while (true) {
      int n0 = r0 + 4096, n1 = n0 + 2048;
      bool more = n0 < V;
      float4 B0[4], B1[4];
      if (more) {
        loadrow(B0, P2, n0, lane);
        loadrow(B1, P2, n1 < V ? n1 : n0, lane);
      }
      float a0 = dot4(A0[0], s4a[lane]) + dot4(A0[1], s4a[lane + 64]) +
                 dot4(A0[2], s4a[lane + 128]) + dot4(A0[3], s4a[lane + 192]);
      float a1 = dot4(A1[0], s4a[lane]) + dot4(A1[1], s4a[lane + 64]) +
                 dot4(A1[2], s4a[lane + 128]) + dot4(A1[3], s4a[lane + 192]);
      a0 = wred(a0); a1 = wred(a1);
      if (lane == 0) {
        out_logits[r0] = a0;
        if (r1 < V) out_logits[r1] = a1;
      }
      if (!more) break;
#pragma unroll
      for (int q = 0; q < 4; ++q) { A0[q] = B0[q]; A1[q] = B1[q]; }
      r0 = n0; r1 = n1;
    }
  }
}

extern "C" void kernel_launch(void *const *d_in, const int *in_sizes, int n_in,
                              void *d_out, int out_size, void *d_ws, size_t ws_size,
                              hipStream_t stream) {
  (void)in_sizes; (void)n_in; (void)out_size; (void)ws_size;
  Args a;
  a.statea = (const float *)d_in[0];
  a.stateb = (const float *)d_in[1];
  a.statec = (const float *)d_in[2];
  a.stated = (const float *)d_in[3];
  a.pre    = (const float *)d_in[4];
  a.ln1w   = (const float *)d_in[5];
  a.ln1b   = (const float *)d_in[6];
  a.ln2w   = (const float *)d_in[7];
  a.ln2b   = (const float *)d_in[8];
  a.ak     = (const float *)d_in[9];
  a.ar     = (const float *)d_in[10];
  a.av     = (const float *)d_in[11];
  a.kk     = (const float *)d_in[12];
  a.vv     = (const float *)d_in[13];
  a.rr     = (const float *)d_in[14];
  a.tf     = (const float *)d_in[15];
  a.td     = (const float *)d_in[16];
  a.ovv    = (const float *)d_in[17];
  a.tmk    = (const float *)d_in[18];
  a.tmr    = (const float *)d_in[19];
  a.kf     = (const float *)d_in[20];
  a.rf     = (const float *)d_in[21];
  a.vf     = (const float *)d_in[22];
  a.post0  = (const float *)d_in[23];
  a.post1  = (const float *)d_in[24];
  a.post2  = (const float *)d_in[25];
  a.token  = (const int *)d_in[26];
  a.out    = (float *)d_out;

  a.flags = (u32 *)d_ws;                          // 256 × 128B = 32 KB
  float *base = (float *)((char *)d_ws + 32768);
  a.wu  = base;          // 1024
  a.wsx = base + 1024;   // 1024
  a.wx  = base + 2048;   // 1024
  a.wkm = base + 3072;   // 4096

  hipMemsetAsync(d_ws, 0, 32768, stream);
  rwkv_fused<<<NBLK, NTHR, 0, stream>>>(a);
}

// Round 10
// 330.265 us; speedup vs baseline: 1.0012x; 1.0012x over previous
//
#include <hip/hip_runtime.h>
#include <math.h>

// RWKV single-token forward — ONE persistent kernel, overlap-preserving sync.
// Round-10 = round-9 architecture with the spill removed:
//  - NO VGPR cap (launch_bounds without min-waves; R9's (512,2) forced <=128
//    VGPR -> 12MB scratch spills in the hot path, 330us).
//  - sched_barrier(0) between gather issue and weight burst: gather is oldest
//    in the vmcnt FIFO, so its counted wait never drains the burst.
//  - Waves 1-7: burst next phase's weights at body top; never drain vmem.
//    Wave 0: publish -> vmcnt(0) (clean queue) -> flag -> own burst -> poll.
//  - All intra-phase syncs lgkmcnt-only (raw s_barrier).

typedef unsigned long long u64;
typedef unsigned u32;

constexpr int E = 1024;
constexpr int H = 4096;
constexpr int V = 50277;
constexpr int L = 12;
constexpr int NBLK = 256;
constexpr int NTHR = 512;
constexpr float LN_EPS = 9.999999747378752e-06f;

#define SA __HIP_MEMORY_SCOPE_AGENT

__device__ __forceinline__ void stf(float *p, float v) {
  __hip_atomic_store(p, v, __ATOMIC_RELAXED, SA);
}
__device__ __forceinline__ void stu(u32 *p, u32 v) {
  __hip_atomic_store(p, v, __ATOMIC_RELAXED, SA);
}
__device__ __forceinline__ u32 ldu(const u32 *p) {
  return __hip_atomic_load(p, __ATOMIC_RELAXED, SA);
}
__device__ __forceinline__ float2 ld2(const float *p) {
  union { u64 u; float2 f; } c;
  c.u = __hip_atomic_load((const u64 *)p, __ATOMIC_RELAXED, SA);
  return c.f;
}

// LDS-only barrier: never drains vmem.
__device__ __forceinline__ void lds_sync() {
  asm volatile("s_waitcnt lgkmcnt(0)" ::: "memory");
  __builtin_amdgcn_s_barrier();
}
__device__ __forceinline__ void vdrain() {
  asm volatile("s_waitcnt vmcnt(0)" ::: "memory");
}
__device__ __forceinline__ void pin() { __builtin_amdgcn_sched_barrier(0); }

struct Args {
  const float *statea, *stateb, *statec, *stated, *pre;
  const float *ln1w, *ln1b, *ln2w, *ln2b;
  const float *ak, *ar, *av, *kk, *vv, *rr, *tf, *td, *ovv;
  const float *tmk, *tmr, *kf, *rf, *vf;
  const float *post0, *post1, *post2;
  const int *token;
  float *out;
  u32 *flags;                    // 256 flags, stride 32 dwords (128 B)
  float *wu, *wsx, *wx, *wkm;    // coherent cross-block vectors
};

__device__ __forceinline__ float wred(float v) {
#pragma unroll
  for (int off = 32; off; off >>= 1) v += __shfl_down(v, off, 64);
  return v;
}
__device__ __forceinline__ float dot4(float4 w, float4 x) {
  return w.x * x.x + w.y * x.y + w.z * x.z + w.w * x.w;
}

// ---- weight bundle loads (issued one phase ahead) ----
struct P1B {
  float4 w[6];
  float2 lw, lb, sa, kk, vv, rr;
  float tf, td, sb, sc;
};
__device__ __forceinline__ void load_p1(P1B &p, const Args &a, int l, int grow,
                                        int b0h, int tid, int blk) {
  const size_t lE = (size_t)l * E;
  const float4 *kr = reinterpret_cast<const float4 *>(a.ak + (lE + grow) * E);
  const float4 *vr = reinterpret_cast<const float4 *>(a.av + (lE + grow) * E);
  const float4 *rr4 = reinterpret_cast<const float4 *>(a.ar + (lE + grow) * E);
  p.w[0] = kr[b0h]; p.w[1] = kr[b0h + 64];
  p.w[2] = vr[b0h]; p.w[3] = vr[b0h + 64];
  p.w[4] = rr4[b0h]; p.w[5] = rr4[b0h + 64];
  p.lw = reinterpret_cast<const float2 *>(a.ln1w + lE)[tid];
  p.lb = reinterpret_cast<const float2 *>(a.ln1b + lE)[tid];
  p.sa = reinterpret_cast<const float2 *>(a.statea + lE)[tid];
  p.kk = reinterpret_cast<const float2 *>(a.kk + lE)[tid];
  p.vv = reinterpret_cast<const float2 *>(a.vv + lE)[tid];
  p.rr = reinterpret_cast<const float2 *>(a.rr + lE)[tid];
  if (tid < 4) {
    size_t o = lE + blk * 4 + tid;
    p.tf = a.tf[o]; p.td = a.td[o]; p.sb = a.stateb[o]; p.sc = a.statec[o];
  } else {
    p.tf = 0.f; p.td = 0.f; p.sb = 0.f; p.sc = 1.f;
  }
}
__device__ __forceinline__ void load_ovv_kf0(float4 po[2], float4 pf[8],
                                             const Args &a, int l, int grow,
                                             int b0h, int blk, int wid, int lane) {
  const size_t lE = (size_t)l * E;
  const float4 *orow = reinterpret_cast<const float4 *>(a.ovv + (lE + grow) * E);
  po[0] = orow[b0h]; po[1] = orow[b0h + 64];
  const float *kfb = a.kf + (size_t)l * H * E;
  const float4 *k0 = reinterpret_cast<const float4 *>(kfb + (size_t)(blk * 16 + wid) * E);
  pf[0] = k0[lane]; pf[1] = k0[lane + 64]; pf[2] = k0[lane + 128]; pf[3] = k0[lane + 192];
}
struct P3B {
  float4 r[2];
  float2 lw, lb, sd, tk, tr;
};
__device__ __forceinline__ void load_kf1_rf(float4 pf[8], P3B &p, const Args &a,
                                            int l, int grow, int b0h, int blk,
                                            int wid, int lane, int tid) {
  const size_t lE = (size_t)l * E;
  const float *kfb = a.kf + (size_t)l * H * E;
  const float4 *k1 = reinterpret_cast<const float4 *>(kfb + (size_t)(blk * 16 + 8 + wid) * E);
  pf[4] = k1[lane]; pf[5] = k1[lane + 64]; pf[6] = k1[lane + 128]; pf[7] = k1[lane + 192];
  const float4 *rrow = reinterpret_cast<const float4 *>(a.rf + (lE + grow) * E);
  p.r[0] = rrow[b0h]; p.r[1] = rrow[b0h + 64];
  p.lw = reinterpret_cast<const float2 *>(a.ln2w + lE)[tid];
  p.lb = reinterpret_cast<const float2 *>(a.ln2b + lE)[tid];
  p.sd = reinterpret_cast<const float2 *>(a.stated + lE)[tid];
  p.tk = reinterpret_cast<const float2 *>(a.tmk + lE)[tid];
  p.tr = reinterpret_cast<const float2 *>(a.tmr + lE)[tid];
}
__device__ __forceinline__ void load_vf(float4 pv[8], const Args &a, int l,
                                        int grow, int bv) {
  const float4 *vrow = reinterpret_cast<const float4 *>(a.vf + ((size_t)l * E + grow) * H);
  pv[0] = vrow[bv];       pv[1] = vrow[bv + 64];
  pv[2] = vrow[bv + 128]; pv[3] = vrow[bv + 192];
  pv[4] = vrow[bv + 256]; pv[5] = vrow[bv + 320];
  pv[6] = vrow[bv + 384]; pv[7] = vrow[bv + 448];
}

// wave-0: poll all 256 flags (4 per lane, 128B stride)
__device__ __forceinline__ void poll_flags(const u32 *flags, unsigned ep, int lane) {
  const u32 *f0 = flags + (lane * 4 + 0) * 32;
  const u32 *f1 = flags + (lane * 4 + 1) * 32;
  const u32 *f2 = flags + (lane * 4 + 2) * 32;
  const u32 *f3 = flags + (lane * 4 + 3) * 32;
  for (;;) {
    u32 a0 = ldu(f0), a1 = ldu(f1), a2 = ldu(f2), a3 = ldu(f3);
    if (a0 >= ep && a1 >= ep && a2 >= ep && a3 >= ep) break;
    __builtin_amdgcn_s_sleep(1);
  }
}

__device__ __forceinline__ void loadrow(float4 *d, const float4 *P, int r, int lane) {
  const float4 *p = P + (size_t)r * 256;
  d[0] = p[lane]; d[1] = p[lane + 64]; d[2] = p[lane + 128]; d[3] = p[lane + 192];
}

__global__ __launch_bounds__(NTHR) void rwkv_fused(Args a) {
  __shared__ __align__(16) float s_a[4096];
  __shared__ __align__(16) float s_x[1024];
  __shared__ float s_red[16];
  __shared__ float s_pp[24];
  __shared__ float s_rt[4];

  const int tid = threadIdx.x;
  const int lane = tid & 63;
  const int wid = tid >> 6;        // 0..7
  const int blk = blockIdx.x;
  const int rloc = wid >> 1;
  const int h = wid & 1;
  const int grow = blk * 4 + rloc;
  const int b0h = h * 128 + lane;
  const int bv = h * 512 + lane;

  float *out_logits = a.out;
  float *out_aaa = a.out + V;
  float *out_bbb = out_aaa + L * E;
  float *out_ccc = out_bbb + L * E;
  float *out_ddd = out_ccc + L * E;

  const int tok = a.token[0];
  const float *pre_row = a.pre + (size_t)tok * E;
  const float4 *s4a = reinterpret_cast<const float4 *>(s_a);

  P1B p1;
  float4 po[2], pf[8], pv[8];
  P3B p3;
  unsigned ep = 1;

  load_p1(p1, a, 0, grow, b0h, tid, blk);

#pragma unroll 1
  for (int l = 0; l < L; ++l) {
    const size_t lE = (size_t)l * E;

    // ================= P1: LN1 + k/v/r matvecs + wkv =================
    {
      float2 xv;
      if (l == 0) xv = reinterpret_cast<const float2 *>(pre_row)[tid];
      else        xv = ld2(a.wx + 2 * tid);
      pin();  // gather is oldest in vmcnt FIFO
      if (wid != 0) load_ovv_kf0(po, pf, a, l, grow, b0h, blk, wid, lane);
      reinterpret_cast<float2 *>(s_x)[tid] = xv;
      float s = xv.x + xv.y, s2 = xv.x * xv.x + xv.y * xv.y;
#pragma unroll
      for (int m = 1; m <= 32; m <<= 1) {
        s += __shfl_xor(s, m, 64);
        s2 += __shfl_xor(s2, m, 64);
      }
      if (lane == 0) { s_red[wid * 2] = s; s_red[wid * 2 + 1] = s2; }
      lds_sync();
      float ts = 0.f, ts2 = 0.f;
#pragma unroll
      for (int i = 0; i < 8; ++i) { ts += s_red[2 * i]; ts2 += s_red[2 * i + 1]; }
      float mn = ts * (1.0f / E);
      float rstd = rsqrtf(ts2 * (1.0f / E) - mn * mn + LN_EPS);
      float2 xy = make_float2((xv.x - mn) * rstd * p1.lw.x + p1.lb.x,
                              (xv.y - mn) * rstd * p1.lw.y + p1.lb.y);
      if ((tid >> 1) == blk) {
        out_aaa[lE + 2 * tid] = xy.x;
        out_aaa[lE + 2 * tid + 1] = xy.y;
      }
      reinterpret_cast<float2 *>(s_a)[tid] =
          make_float2(xy.x + p1.kk.x * p1.sa.x, xy.y + p1.kk.y * p1.sa.y);
      reinterpret_cast<float2 *>(s_a + 1024)[tid] =
          make_float2(xy.x + p1.vv.x * p1.sa.x, xy.y + p1.vv.y * p1.sa.y);
      reinterpret_cast<float2 *>(s_a + 2048)[tid] =
          make_float2(xy.x + p1.rr.x * p1.sa.x, xy.y + p1.rr.y * p1.sa.y);
      lds_sync();
      float accK = dot4(p1.w[0], s4a[b0h]) + dot4(p1.w[1], s4a[b0h + 64]);
      float accV = dot4(p1.w[2], s4a[256 + b0h]) + dot4(p1.w[3], s4a[256 + b0h + 64]);
      float accR = dot4(p1.w[4], s4a[512 + b0h]) + dot4(p1.w[5], s4a[512 + b0h + 64]);
      accK = wred(accK); accV = wred(accV); accR = wred(accR);
      if (lane == 0) {
        s_pp[wid * 3 + 0] = accK;
        s_pp[wid * 3 + 1] = accV;
        s_pp[wid * 3 + 2] = accR;
      }
      lds_sync();
      if (wid == 0) {
        int i = lane & 3;
        float K = s_pp[(2 * i) * 3] + s_pp[(2 * i + 1) * 3];
        float Vv = s_pp[(2 * i) * 3 + 1] + s_pp[(2 * i + 1) * 3 + 1];
        float R = s_pp[(2 * i) * 3 + 2] + s_pp[(2 * i + 1) * 3 + 2];
        if (lane < 4) {
          size_t o = lE + blk * 4 + lane;
          float kx = expf(K), rx = expf(R) + 1.0f;
          float etf = expf(p1.tf), etd = expf(p1.td);
          float w_ = p1.sb + etf * kx * Vv;
          float d_ = p1.sc * rx + etf * kx * rx;
          stf(a.wu + blk * 4 + lane, w_ / (d_ + 0.001f));
          out_bbb[o] = p1.sb * etd + kx * Vv;
          out_ccc[o] = p1.sc * etd + kx;
        }
        vdrain();
        if (lane == 0) stu(a.flags + blk * 32, ep);
        load_ovv_kf0(po, pf, a, l, grow, b0h, blk, wid, lane);
        poll_flags(a.flags, ep, lane);
      }
      lds_sync(); ++ep;
    }

    // ================= P2: sxx = x + ovv @ u =================
    {
      float2 u2 = ld2(a.wu + 2 * tid);
      pin();
      if (wid != 0) load_kf1_rf(pf, p3, a, l, grow, b0h, blk, wid, lane, tid);
      reinterpret_cast<float2 *>(s_a)[tid] = u2;
      lds_sync();
      float acc = dot4(po[0], s4a[b0h]) + dot4(po[1], s4a[b0h + 64]);
      acc = wred(acc);
      if (lane == 0) s_pp[wid] = acc;
      lds_sync();
      if (wid == 0) {
        int i = lane & 3;
        float sxx = s_x[blk * 4 + i] + s_pp[2 * i] + s_pp[2 * i + 1];
        if (lane < 4) stf(a.wsx + blk * 4 + lane, sxx);
        vdrain();
        if (lane == 0) stu(a.flags + blk * 32, ep);
        load_kf1_rf(pf, p3, a, l, grow, b0h, blk, wid, lane, tid);
        poll_flags(a.flags, ep, lane);
      }
      lds_sync(); ++ep;
    }

    // ================= P3: LN2 + key_ffn + receptance_ffn =================
    {
      float2 sxv = ld2(a.wsx + 2 * tid);
      pin();
      if (wid != 0) load_vf(pv, a, l, grow, bv);
      reinterpret_cast<float2 *>(s_x)[tid] = sxv;
      float s = sxv.x + sxv.y, s2 = sxv.x * sxv.x + sxv.y * sxv.y;
#pragma unroll
      for (int m = 1; m <= 32; m <<= 1) {
        s += __shfl_xor(s, m, 64);
        s2 += __shfl_xor(s2, m, 64);
      }
      if (lane == 0) { s_red[wid * 2] = s; s_red[wid * 2 + 1] = s2; }
      lds_sync();
      float ts = 0.f, ts2 = 0.f;
#pragma unroll
      for (int i = 0; i < 8; ++i) { ts += s_red[2 * i]; ts2 += s_red[2 * i + 1]; }
      float mn = ts * (1.0f / E);
      float rstd = rsqrtf(ts2 * (1.0f / E) - mn * mn + LN_EPS);
      float2 xx = make_float2((sxv.x - mn) * rstd * p3.lw.x + p3.lb.x,
                              (sxv.y - mn) * rstd * p3.lw.y + p3.lb.y);
      if ((tid >> 1) == blk) {
        out_ddd[lE + 2 * tid] = xx.x;
        out_ddd[lE + 2 * tid + 1] = xx.y;
      }
      reinterpret_cast<float2 *>(s_a)[tid] =
          make_float2(xx.x + p3.tk.x * p3.sd.x, xx.y + p3.tk.y * p3.sd.y);
      reinterpret_cast<float2 *>(s_a + 1024)[tid] =
          make_float2(xx.x + p3.tr.x * p3.sd.x, xx.y + p3.tr.y * p3.sd.y);
      lds_sync();
      float k0 = 0.f, k1 = 0.f;
#pragma unroll
      for (int it = 0; it < 4; ++it) {
        float4 xv4 = s4a[it * 64 + lane];
        k0 += dot4(pf[it], xv4);
        k1 += dot4(pf[4 + it], xv4);
      }
      float ar_ = dot4(p3.r[0], s4a[256 + b0h]) + dot4(p3.r[1], s4a[256 + b0h + 64]);
      k0 = wred(k0); k1 = wred(k1); ar_ = wred(ar_);
      if (lane == 0) {
        s_pp[wid * 3 + 0] = k0;
        s_pp[wid * 3 + 1] = k1;
        s_pp[wid * 3 + 2] = ar_;
      }
      lds_sync();
      if (wid == 0) {
        if (lane < 4) {
          float arsum = s_pp[(2 * lane) * 3 + 2] + s_pp[(2 * lane + 1) * 3 + 2];
          s_rt[lane] = expf(arsum) + 1.0f;
        }
        if (lane < 16) {
          int w = lane & 7, sel = (lane >> 3) & 1;
          float kv = s_pp[w * 3 + sel];
          float t = fmaxf(kv, 0.f);
          stf(a.wkm + blk * 16 + sel * 8 + w, t * t);
        }
        vdrain();
        if (lane == 0) stu(a.flags + blk * 32, ep);
        load_vf(pv, a, l, grow, bv);
        poll_flags(a.flags, ep, lane);
      }
      lds_sync(); ++ep;
    }

    // ================= P4: x_next = sxx + (vf @ km) / rt =================
    {
      const u64 *km64 = reinterpret_cast<const u64 *>(a.wkm);
      union { u64 u; float2 f; } g0, g1, g2, g3;
      g0.u = __hip_atomic_load(km64 + 2 * tid, __ATOMIC_RELAXED, SA);
      g1.u = __hip_atomic_load(km64 + 2 * tid + 1, __ATOMIC_RELAXED, SA);
      g2.u = __hip_atomic_load(km64 + 1024 + 2 * tid, __ATOMIC_RELAXED, SA);
      g3.u = __hip_atomic_load(km64 + 1024 + 2 * tid + 1, __ATOMIC_RELAXED, SA);
      pin();
      if (wid != 0) {
        if (l + 1 < L) {
          load_p1(p1, a, l + 1, grow, b0h, tid, blk);
        } else {
          p1.lw = reinterpret_cast<const float2 *>(a.post0)[tid];
          p1.lb = reinterpret_cast<const float2 *>(a.post1)[tid];
        }
      }
      reinterpret_cast<float2 *>(s_a)[2 * tid] = g0.f;
      reinterpret_cast<float2 *>(s_a)[2 * tid + 1] = g1.f;
      reinterpret_cast<float2 *>(s_a)[1024 + 2 * tid] = g2.f;
      reinterpret_cast<float2 *>(s_a)[1024 + 2 * tid + 1] = g3.f;
      lds_sync();
      float acc = 0.f;
#pragma unroll
      for (int it = 0; it < 8; ++it) acc += dot4(pv[it], s4a[bv + it * 64]);
      acc = wred(acc);
      if (lane == 0) s_pp[wid] = acc;
      lds_sync();
      if (wid == 0) {
        int i = lane & 3;
        float xn = s_x[blk * 4 + i] + (s_pp[2 * i] + s_pp[2 * i + 1]) / s_rt[i];
        if (lane < 4) stf(a.wx + blk * 4 + lane, xn);
        vdrain();
        if (lane == 0) stu(a.flags + blk * 32, ep);
        if (l + 1 < L) {
          load_p1(p1, a, l + 1, grow, b0h, tid, blk);
        } else {
          p1.lw = reinterpret_cast<const float2 *>(a.post0)[tid];
          p1.lb = reinterpret_cast<const float2 *>(a.post1)[tid];
        }
        poll_flags(a.flags, ep, lane);
      }
      lds_sync(); ++ep;
    }
  }

  // ================= Final: LN + logits (double-buffered) =================
  {
    float2 xv = ld2(a.wx + 2 * tid);
    reinterpret_cast<float2 *>(s_x)[tid] = xv;
    float s = xv.x + xv.y, s2 = xv.x * xv.x + xv.y * xv.y;
#pragma unroll
    for (int m = 1; m <= 32; m <<= 1) {
      s += __shfl_xor(s, m, 64);
      s2 += __shfl_xor(s2, m, 64);
    }
    if (lane == 0) { s_red[wid * 2] = s; s_red[wid * 2 + 1] = s2; }
    lds_sync();
    float ts = 0.f, ts2 = 0.f;
#pragma unroll
    for (int i = 0; i < 8; ++i) { ts += s_red[2 * i]; ts2 += s_red[2 * i + 1]; }
    float mn = ts * (1.0f / E);
    float rstd = rsqrtf(ts2 * (1.0f / E) - mn * mn + LN_EPS);
    reinterpret_cast<float2 *>(s_a)[tid] =
        make_float2((xv.x - mn) * rstd * p1.lw.x + p1.lb.x,
                    (xv.y - mn) * rstd * p1.lw.y + p1.lb.y);
    lds_sync();

    const float4 *P2 = reinterpret_cast<const float4 *>(a.post2);
    const int gw = blk * 8 + wid;  // 0..2047
    int r0 = gw, r1 = gw + 2048;
    float4 A0[4], A1[4];
    loadrow(A0, P2, r0, lane);
    loadrow(A1, P2, r1 < V ? r1 : r0, lane);
    while (true) {
      int n0 = r0 + 4096, n1 = n0 + 2048;
      bool more = n0 < V;
      float4 B0[4], B1[4];
      if (more) {
        loadrow(B0, P2, n0, lane);
        loadrow(B1, P2, n1 < V ? n1 : n0, lane);
      }
      float a0 = dot4(A0[0], s4a[lane]) + dot4(A0[1], s4a[lane + 64]) +
                 dot4(A0[2], s4a[lane + 128]) + dot4(A0[3], s4a[lane + 192]);
      float a1 = dot4(A1[0], s4a[lane]) + dot4(A1[1], s4a[lane + 64]) +
                 dot4(A1[2], s4a[lane + 128]) + dot4(A1[3], s4a[lane + 192]);
      a0 = wred(a0); a1 = wred(a1);
      if (lane == 0) {
        out_logits[r0] = a0;
        if (r1 < V) out_logits[r1] = a1;
      }
      if (!more) break;
#pragma unroll
      for (int q = 0; q < 4; ++q) { A0[q] = B0[q]; A1[q] = B1[q]; }
      r0 = n0; r1 = n1;
    }
  }
}

extern "C" void kernel_launch(void *const *d_in, const int *in_sizes, int n_in,
                              void *d_out, int out_size, void *d_ws, size_t ws_size,
                              hipStream_t stream) {
  (void)in_sizes; (void)n_in; (void)out_size; (void)ws_size;
  Args a;
  a.statea = (const float *)d_in[0];
  a.stateb = (const float *)d_in[1];
  a.statec = (const float *)d_in[2];
  a.stated = (const float *)d_in[3];
  a.pre    = (const float *)d_in[4];
  a.ln1w   = (const float *)d_in[5];
  a.ln1b   = (const float *)d_in[6];
  a.ln2w   = (const float *)d_in[7];
  a.ln2b   = (const float *)d_in[8];
  a.ak     = (const float *)d_in[9];
  a.ar     = (const float *)d_in[10];
  a.av     = (const float *)d_in[11];
  a.kk     = (const float *)d_in[12];
  a.vv     = (const float *)d_in[13];
  a.rr     = (const float *)d_in[14];
  a.tf     = (const float *)d_in[15];
  a.td     = (const float *)d_in[16];
  a.ovv    = (const float *)d_in[17];
  a.tmk    = (const float *)d_in[18];
  a.tmr    = (const float *)d_in[19];
  a.kf     = (const float *)d_in[20];
  a.rf     = (const float *)d_in[21];
  a.vf     = (const float *)d_in[22];
  a.post0  = (const float *)d_in[23];
  a.post1  = (const float *)d_in[24];
  a.post2  = (const float *)d_in[25];
  a.token  = (const int *)d_in[26];
  a.out    = (float *)d_out;

  a.flags = (u32 *)d_ws;                          // 256 × 128B = 32 KB
  float *base = (float *)((char *)d_ws + 32768);
  a.wu  = base;          // 1024
  a.wsx = base + 1024;   // 1024
  a.wx  = base + 2048;   // 1024
  a.wkm = base + 3072;   // 4096

  hipMemsetAsync(d_ws, 0, 32768, stream);
  rwkv_fused<<<NBLK, NTHR, 0, stream>>>(a);
}

// Round 11
// 256.067 us; speedup vs baseline: 1.2914x; 1.2898x over previous
//
#include <hip/hip_runtime.h>
#include <math.h>

// RWKV single-token forward — ONE persistent kernel, single-gatherer protocol.
// Wave 0 is the only wave that touches cross-block traffic:
//   publish (lanes<4) -> wave-local vmcnt(0) -> flag -> own weight share ->
//   poll 256 flags -> gather the whole vector into LDS (+ LN stats in-wave).
// Waves 1-7: issue weight burst at ONE site, wait at LDS-only barriers; their
// vmcnt FIFO is never drained by gathers/barriers -> weight streams span the
// whole phase. Register-lean: one gather temp set (wave 0), no duplicated
// bundle loads (R9/R10's spill cause).

typedef unsigned long long u64;
typedef unsigned u32;

constexpr int E = 1024;
constexpr int H = 4096;
constexpr int V = 50277;
constexpr int L = 12;
constexpr int NBLK = 256;
constexpr int NTHR = 512;
constexpr float LN_EPS = 9.999999747378752e-06f;

#define SA __HIP_MEMORY_SCOPE_AGENT

__device__ __forceinline__ void stf(float *p, float v) {
  __hip_atomic_store(p, v, __ATOMIC_RELAXED, SA);
}
__device__ __forceinline__ void stu(u32 *p, u32 v) {
  __hip_atomic_store(p, v, __ATOMIC_RELAXED, SA);
}
__device__ __forceinline__ u32 ldu(const u32 *p) {
  return __hip_atomic_load(p, __ATOMIC_RELAXED, SA);
}

// LDS-only barrier: never drains vmem.
__device__ __forceinline__ void lds_sync() {
  asm volatile("s_waitcnt lgkmcnt(0)" ::: "memory");
  __builtin_amdgcn_s_barrier();
}
__device__ __forceinline__ void vdrain() {
  asm volatile("s_waitcnt vmcnt(0)" ::: "memory");
}

struct Args {
  const float *statea, *stateb, *statec, *stated, *pre;
  const float *ln1w, *ln1b, *ln2w, *ln2b;
  const float *ak, *ar, *av, *kk, *vv, *rr, *tf, *td, *ovv;
  const float *tmk, *tmr, *kf, *rf, *vf;
  const float *post0, *post1, *post2;
  const int *token;
  float *out;
  u32 *flags;                    // 256 flags, stride 32 dwords (128 B)
  float *wu, *wsx, *wx, *wkm;    // coherent cross-block vectors
};

__device__ __forceinline__ float wred(float v) {
#pragma unroll
  for (int off = 32; off; off >>= 1) v += __shfl_down(v, off, 64);
  return v;
}
__device__ __forceinline__ float dot4(float4 w, float4 x) {
  return w.x * x.x + w.y * x.y + w.z * x.z + w.w * x.w;
}

// Coherent gather of 1024 floats by one wave into LDS; optional LN stats
// computed wave-internally (mean/rstd -> s_red[0..1]).
__device__ __forceinline__ void gather1024(const float *src, float *dst,
                                           int lane, bool do_stats,
                                           float *s_red) {
  const float4 *s4 = reinterpret_cast<const float4 *>(src);
  float4 g0, g1, g2, g3;
  const float4 *q0 = s4 + lane, *q1 = s4 + lane + 64;
  const float4 *q2 = s4 + lane + 128, *q3 = s4 + lane + 192;
  asm volatile(
      "global_load_dwordx4 %0, %4, off sc0 sc1\n\t"
      "global_load_dwordx4 %1, %5, off sc0 sc1\n\t"
      "global_load_dwordx4 %2, %6, off sc0 sc1\n\t"
      "global_load_dwordx4 %3, %7, off sc0 sc1\n\t"
      "s_waitcnt vmcnt(0)"
      : "=&v"(g0), "=&v"(g1), "=&v"(g2), "=&v"(g3)
      : "v"(q0), "v"(q1), "v"(q2), "v"(q3)
      : "memory");
  float4 *d4 = reinterpret_cast<float4 *>(dst);
  d4[lane] = g0; d4[lane + 64] = g1; d4[lane + 128] = g2; d4[lane + 192] = g3;
  if (do_stats) {
    float s = g0.x + g0.y + g0.z + g0.w + g1.x + g1.y + g1.z + g1.w +
              g2.x + g2.y + g2.z + g2.w + g3.x + g3.y + g3.z + g3.w;
    float s2 = g0.x * g0.x + g0.y * g0.y + g0.z * g0.z + g0.w * g0.w +
               g1.x * g1.x + g1.y * g1.y + g1.z * g1.z + g1.w * g1.w +
               g2.x * g2.x + g2.y * g2.y + g2.z * g2.z + g2.w * g2.w +
               g3.x * g3.x + g3.y * g3.y + g3.z * g3.z + g3.w * g3.w;
#pragma unroll
    for (int m = 1; m <= 32; m <<= 1) {
      s += __shfl_xor(s, m, 64);
      s2 += __shfl_xor(s2, m, 64);
    }
    if (lane == 0) {
      float mn = s * (1.0f / E);
      float rstd = rsqrtf(s2 * (1.0f / E) - mn * mn + LN_EPS);
      s_red[0] = mn; s_red[1] = rstd;
    }
  }
}

// ---- weight bundles (one load site per phase, all waves) ----
struct P1B {
  float4 w[6];
  float2 lw, lb, sa, kk, vv, rr;
  float tf, td, sb, sc;
};
__device__ __forceinline__ void load_p1(P1B &p, const Args &a, int l, int grow,
                                        int b0h, int tid, int blk) {
  const size_t lE = (size_t)l * E;
  const float4 *kr = reinterpret_cast<const float4 *>(a.ak + (lE + grow) * E);
  const float4 *vr = reinterpret_cast<const float4 *>(a.av + (lE + grow) * E);
  const float4 *rr4 = reinterpret_cast<const float4 *>(a.ar + (lE + grow) * E);
  p.w[0] = kr[b0h]; p.w[1] = kr[b0h + 64];
  p.w[2] = vr[b0h]; p.w[3] = vr[b0h + 64];
  p.w[4] = rr4[b0h]; p.w[5] = rr4[b0h + 64];
  p.lw = reinterpret_cast<const float2 *>(a.ln1w + lE)[tid];
  p.lb = reinterpret_cast<const float2 *>(a.ln1b + lE)[tid];
  p.sa = reinterpret_cast<const float2 *>(a.statea + lE)[tid];
  p.kk = reinterpret_cast<const float2 *>(a.kk + lE)[tid];
  p.vv = reinterpret_cast<const float2 *>(a.vv + lE)[tid];
  p.rr = reinterpret_cast<const float2 *>(a.rr + lE)[tid];
  if (tid < 4) {
    size_t o = lE + blk * 4 + tid;
    p.tf = a.tf[o]; p.td = a.td[o]; p.sb = a.stateb[o]; p.sc = a.statec[o];
  } else {
    p.tf = 0.f; p.td = 0.f; p.sb = 0.f; p.sc = 1.f;
  }
}
__device__ __forceinline__ void load_ovv_kf0(float4 po[2], float4 pf[8],
                                             const Args &a, int l, int grow,
                                             int b0h, int blk, int wid, int lane) {
  const size_t lE = (size_t)l * E;
  const float4 *orow = reinterpret_cast<const float4 *>(a.ovv + (lE + grow) * E);
  po[0] = orow[b0h]; po[1] = orow[b0h + 64];
  const float *kfb = a.kf + (size_t)l * H * E;
  const float4 *k0 = reinterpret_cast<const float4 *>(kfb + (size_t)(blk * 16 + wid) * E);
  pf[0] = k0[lane]; pf[1] = k0[lane + 64]; pf[2] = k0[lane + 128]; pf[3] = k0[lane + 192];
}
struct P3B {
  float4 r[2];
  float2 lw, lb, sd, tk, tr;
};
__device__ __forceinline__ void load_kf1_rf(float4 pf[8], P3B &p, const Args &a,
                                            int l, int grow, int b0h, int blk,
                                            int wid, int lane, int tid) {
  const size_t lE = (size_t)l * E;
  const float *kfb = a.kf + (size_t)l * H * E;
  const float4 *k1 = reinterpret_cast<const float4 *>(kfb + (size_t)(blk * 16 + 8 + wid) * E);
  pf[4] = k1[lane]; pf[5] = k1[lane + 64]; pf[6] = k1[lane + 128]; pf[7] = k1[lane + 192];
  const float4 *rrow = reinterpret_cast<const float4 *>(a.rf + (lE + grow) * E);
  p.r[0] = rrow[b0h]; p.r[1] = rrow[b0h + 64];
  p.lw = reinterpret_cast<const float2 *>(a.ln2w + lE)[tid];
  p.lb = reinterpret_cast<const float2 *>(a.ln2b + lE)[tid];
  p.sd = reinterpret_cast<const float2 *>(a.stated + lE)[tid];
  p.tk = reinterpret_cast<const float2 *>(a.tmk + lE)[tid];
  p.tr = reinterpret_cast<const float2 *>(a.tmr + lE)[tid];
}
__device__ __forceinline__ void load_vf(float4 pv[8], const Args &a, int l,
                                        int grow, int bv) {
  const float4 *vrow = reinterpret_cast<const float4 *>(a.vf + ((size_t)l * E + grow) * H);
  pv[0] = vrow[bv];       pv[1] = vrow[bv + 64];
  pv[2] = vrow[bv + 128]; pv[3] = vrow[bv + 192];
  pv[4] = vrow[bv + 256]; pv[5] = vrow[bv + 320];
  pv[6] = vrow[bv + 384]; pv[7] = vrow[bv + 448];
}

// wave-0 only: poll all 256 flags (4 per lane, 128 B stride)
__device__ __forceinline__ void poll_flags(const u32 *flags, unsigned ep, int lane) {
  const u32 *f0 = flags + (lane * 4 + 0) * 32;
  const u32 *f1 = flags + (lane * 4 + 1) * 32;
  const u32 *f2 = flags + (lane * 4 + 2) * 32;
  const u32 *f3 = flags + (lane * 4 + 3) * 32;
  for (;;) {
    u32 a0 = ldu(f0), a1 = ldu(f1), a2 = ldu(f2), a3 = ldu(f3);
    if (a0 >= ep && a1 >= ep && a2 >= ep && a3 >= ep) break;
    __builtin_amdgcn_s_sleep(1);
  }
}

__device__ __forceinline__ void loadrow(float4 *d, const float4 *P, int r, int lane) {
  const float4 *p = P + (size_t)r * 256;
  d[0] = p[lane]; d[1] = p[lane + 64]; d[2] = p[lane + 128]; d[3] = p[lane + 192];
}

__global__ __launch_bounds__(NTHR) void rwkv_fused(Args a) {
  __shared__ __align__(16) float s_a[4096];
  __shared__ __align__(16) float s_x[1024];
  __shared__ float s_red[16];
  __shared__ float s_pp[24];
  __shared__ float s_rt[4];

  const int tid = threadIdx.x;
  const int lane = tid & 63;
  const int wid = tid >> 6;        // 0..7
  const int blk = blockIdx.x;
  const int rloc = wid >> 1;
  const int h = wid & 1;
  const int grow = blk * 4 + rloc;
  const int b0h = h * 128 + lane;
  const int bv = h * 512 + lane;

  float *out_logits = a.out;
  float *out_aaa = a.out + V;
  float *out_bbb = out_aaa + L * E;
  float *out_ccc = out_bbb + L * E;
  float *out_ddd = out_ccc + L * E;

  const int tok = a.token[0];
  const float *pre_row = a.pre + (size_t)tok * E;
  const float4 *s4a = reinterpret_cast<const float4 *>(s_a);

  P1B p1;
  float4 po[2], pf[8], pv[8];
  P3B p3;
  unsigned ep = 1;

  load_p1(p1, a, 0, grow, b0h, tid, blk);

#pragma unroll 1
  for (int l = 0; l < L; ++l) {
    const size_t lE = (size_t)l * E;

    // ================= P1: LN1 + k/v/r matvecs + wkv =================
    {
      if (wid == 0) {
        // (for l>0 the poll for epoch 4l already happened at P4's end)
        gather1024(l == 0 ? pre_row : a.wx, s_x, lane, true, s_red);
      }
      lds_sync();  // BAR_A: data + stats visible
      float mn = s_red[0], rstd = s_red[1];
      float2 xv = reinterpret_cast<const float2 *>(s_x)[tid];
      float2 xy = make_float2((xv.x - mn) * rstd * p1.lw.x + p1.lb.x,
                              (xv.y - mn) * rstd * p1.lw.y + p1.lb.y);
      if ((tid >> 1) == blk) {
        out_aaa[lE + 2 * tid] = xy.x;
        out_aaa[lE + 2 * tid + 1] = xy.y;
      }
      reinterpret_cast<float2 *>(s_a)[tid] =
          make_float2(xy.x + p1.kk.x * p1.sa.x, xy.y + p1.kk.y * p1.sa.y);
      reinterpret_cast<float2 *>(s_a + 1024)[tid] =
          make_float2(xy.x + p1.vv.x * p1.sa.x, xy.y + p1.vv.y * p1.sa.y);
      reinterpret_cast<float2 *>(s_a + 2048)[tid] =
          make_float2(xy.x + p1.rr.x * p1.sa.x, xy.y + p1.rr.y * p1.sa.y);
      lds_sync();  // BAR_B: mix vectors ready
      float accK = dot4(p1.w[0], s4a[b0h]) + dot4(p1.w[1], s4a[b0h + 64]);
      float accV = dot4(p1.w[2], s4a[256 + b0h]) + dot4(p1.w[3], s4a[256 + b0h + 64]);
      float accR = dot4(p1.w[4], s4a[512 + b0h]) + dot4(p1.w[5], s4a[512 + b0h + 64]);
      accK = wred(accK); accV = wred(accV); accR = wred(accR);
      if (lane == 0) {
        s_pp[wid * 3 + 0] = accK;
        s_pp[wid * 3 + 1] = accV;
        s_pp[wid * 3 + 2] = accR;
      }
      lds_sync();  // BAR_C: partials ready
      if (wid == 0) {
        if (lane < 4) {
          int i = lane;
          float K = s_pp[(2 * i) * 3] + s_pp[(2 * i + 1) * 3];
          float Vv = s_pp[(2 * i) * 3 + 1] + s_pp[(2 * i + 1) * 3 + 1];
          float R = s_pp[(2 * i) * 3 + 2] + s_pp[(2 * i + 1) * 3 + 2];
          size_t o = lE + blk * 4 + i;
          float kx = expf(K), rx = expf(R) + 1.0f;
          float etf = expf(p1.tf), etd = expf(p1.td);
          float w_ = p1.sb + etf * kx * Vv;
          float d_ = p1.sc * rx + etf * kx * rx;
          stf(a.wu + blk * 4 + i, w_ / (d_ + 0.001f));
          out_bbb[o] = p1.sb * etd + kx * Vv;
          out_ccc[o] = p1.sc * etd + kx;
        }
        vdrain();
        if (lane == 0) stu(a.flags + blk * 32, ep);
        load_ovv_kf0(po, pf, a, l, grow, b0h, blk, wid, lane);
        asm volatile("" ::: "memory");
        poll_flags(a.flags, ep, lane);
      } else {
        load_ovv_kf0(po, pf, a, l, grow, b0h, blk, wid, lane);
        asm volatile("" ::: "memory");
      }
      ++ep;
    }

    // ================= P2: sxx = x + ovv @ u =================
    {
      if (wid == 0) gather1024(a.wu, s_a, lane, false, nullptr);
      lds_sync();  // BAR_A2
      float acc = dot4(po[0], s4a[b0h]) + dot4(po[1], s4a[b0h + 64]);
      acc = wred(acc);
      if (lane == 0) s_pp[wid] = acc;
      lds_sync();  // BAR_B2
      if (wid == 0) {
        if (lane < 4) {
          float sxx = s_x[blk * 4 + lane] + s_pp[2 * lane] + s_pp[2 * lane + 1];
          stf(a.wsx + blk * 4 + lane, sxx);
        }
        vdrain();
        if (lane == 0) stu(a.flags + blk * 32, ep);
        load_kf1_rf(pf, p3, a, l, grow, b0h, blk, wid, lane, tid);
        asm volatile("" ::: "memory");
        poll_flags(a.flags, ep, lane);
      } else {
        load_kf1_rf(pf, p3, a, l, grow, b0h, blk, wid, lane, tid);
        asm volatile("" ::: "memory");
      }
      ++ep;
    }

    // ================= P3: LN2 + key_ffn + receptance_ffn =================
    {
      if (wid == 0) gather1024(a.wsx, s_x, lane, true, s_red);
      lds_sync();  // BAR_A3
      float mn = s_red[0], rstd = s_red[1];
      float2 sxv = reinterpret_cast<const float2 *>(s_x)[tid];
      float2 xx = make_float2((sxv.x - mn) * rstd * p3.lw.x + p3.lb.x,
                              (sxv.y - mn) * rstd * p3.lw.y + p3.lb.y);
      if ((tid >> 1) == blk) {
        out_ddd[lE + 2 * tid] = xx.x;
        out_ddd[lE + 2 * tid + 1] = xx.y;
      }
      reinterpret_cast<float2 *>(s_a)[tid] =
          make_float2(xx.x + p3.tk.x * p3.sd.x, xx.y + p3.tk.y * p3.sd.y);
      reinterpret_cast<float2 *>(s_a + 1024)[tid] =
          make_float2(xx.x + p3.tr.x * p3.sd.x, xx.y + p3.tr.y * p3.sd.y);
      lds_sync();  // BAR_B3
      float k0 = 0.f, k1 = 0.f;
#pragma unroll
      for (int it = 0; it < 4; ++it) {
        float4 xv4 = s4a[it * 64 + lane];
        k0 += dot4(pf[it], xv4);
        k1 += dot4(pf[4 + it], xv4);
      }
      float ar_ = dot4(p3.r[0], s4a[256 + b0h]) + dot4(p3.r[1], s4a[256 + b0h + 64]);
      k0 = wred(k0); k1 = wred(k1); ar_ = wred(ar_);
      if (lane == 0) {
        s_pp[wid * 3 + 0] = k0;
        s_pp[wid * 3 + 1] = k1;
        s_pp[wid * 3 + 2] = ar_;
      }
      lds_sync();  // BAR_C3
      if (wid == 0) {
        if (lane < 4) {
          float ars = s_pp[(2 * lane) * 3 + 2] + s_pp[(2 * lane + 1) * 3 + 2];
          s_rt[lane] = expf(ars) + 1.0f;
        }
        if (lane < 16) {
          int w = lane & 7, sel = (lane >> 3) & 1;
          float kv = s_pp[w * 3 + sel];
          float t = fmaxf(kv, 0.f);
          stf(a.wkm + blk * 16 + sel * 8 + w, t * t);
        }
        vdrain();
        if (lane == 0) stu(a.flags + blk * 32, ep);
        load_vf(pv, a, l, grow, bv);
        asm volatile("" ::: "memory");
        poll_flags(a.flags, ep, lane);
      } else {
        load_vf(pv, a, l, grow, bv);
        asm volatile("" ::: "memory");
      }
      ++ep;
    }

    // ================= P4: x_next = sxx + (vf @ km) / rt =================
    {
      lds_sync();  // BAR_D: gate waves 1-3's gather on wave 0's poll
      if (wid < 4)
        gather1024(a.wkm + wid * 1024, s_a + wid * 1024, lane, false, nullptr);
      lds_sync();  // BAR_A4: km staged
      float acc = 0.f;
#pragma unroll
      for (int it = 0; it < 8; ++it) acc += dot4(pv[it], s4a[bv + it * 64]);
      acc = wred(acc);
      if (lane == 0) s_pp[wid] = acc;
      lds_sync();  // BAR_B4
      if (wid == 0) {
        if (lane < 4) {
          float xn = s_x[blk * 4 + lane] +
                     (s_pp[2 * lane] + s_pp[2 * lane + 1]) / s_rt[lane];
          stf(a.wx + blk * 4 + lane, xn);
        }
        vdrain();
        if (lane == 0) stu(a.flags + blk * 32, ep);
        if (l + 1 < L) {
          load_p1(p1, a, l + 1, grow, b0h, tid, blk);
        } else {
          p1.lw = reinterpret_cast<const float2 *>(a.post0)[tid];
          p1.lb = reinterpret_cast<const float2 *>(a.post1)[tid];
        }
        asm volatile("" ::: "memory");
        poll_flags(a.flags, ep, lane);
      } else {
        if (l + 1 < L) {
          load_p1(p1, a, l + 1, grow, b0h, tid, blk);
        } else {
          p1.lw = reinterpret_cast<const float2 *>(a.post0)[tid];
          p1.lb = reinterpret_cast<const float2 *>(a.post1)[tid];
        }
        asm volatile("" ::: "memory");
      }
      ++ep;
    }
  }

  // ================= Final: LN + logits (double-buffered) =================
  {
    if (wid == 0) gather1024(a.wx, s_x, lane, true, s_red);
    lds_sync();
    float mn = s_red[0], rstd = s_red[1];
    float2 xv = reinterpret_cast<const float2 *>(s_x)[tid];
    reinterpret_cast<float2 *>(s_a)[tid] =
        make_float2((xv.x - mn) * rstd * p1.lw.x + p1.lb.x,
                    (xv.y - mn) * rstd * p1.lw.y + p1.lb.y);
    lds_sync();

    const float4 *P2 = reinterpret_cast<const float4 *>(a.post2);
    const int gw = blk * 8 + wid;  // 0..2047
    int r0 = gw, r1 = gw + 2048;
    float4 A0[4], A1[4];
    loadrow(A0, P2, r0, lane);
    loadrow(A1, P2, r1 < V ? r1 : r0, lane);
    while (true) {
      int n0 = r0 + 4096, n1 = n0 + 2048;
      bool more = n0 < V;
      float4 B0[4], B1[4];
      if (more) {
        loadrow(B0, P2, n0, lane);
        loadrow(B1, P2, n1 < V ? n1 : n0, lane);
      }
      float a0 = dot4(A0[0], s4a[lane]) + dot4(A0[1], s4a[lane + 64]) +
                 dot4(A0[2], s4a[lane + 128]) + dot4(A0[3], s4a[lane + 192]);
      float a1 = dot4(A1[0], s4a[lane]) + dot4(A1[1], s4a[lane + 64]) +
                 dot4(A1[2], s4a[lane + 128]) + dot4(A1[3], s4a[lane + 192]);
      a0 = wred(a0); a1 = wred(a1);
      if (lane == 0) {
        out_logits[r0] = a0;
        if (r1 < V) out_logits[r1] = a1;
      }
      if (!more) break;
#pragma unroll
      for (int q = 0; q < 4; ++q) { A0[q] = B0[q]; A1[q] = B1[q]; }
      r0 = n0; r1 = n1;
    }
  }
}

extern "C" void kernel_launch(void *const *d_in, const int *in_sizes, int n_in,
                              void *d_out, int out_size, void *d_ws, size_t ws_size,
                              hipStream_t stream) {
  (void)in_sizes; (void)n_in; (void)out_size; (void)ws_size;
  Args a;
  a.statea = (const float *)d_in[0];
  a.stateb = (const float *)d_in[1];
  a.statec = (const float *)d_in[2];
  a.stated = (const float *)d_in[3];
  a.pre    = (const float *)d_in[4];
  a.ln1w   = (const float *)d_in[5];
  a.ln1b   = (const float *)d_in[6];
  a.ln2w   = (const float *)d_in[7];
  a.ln2b   = (const float *)d_in[8];
  a.ak     = (const float *)d_in[9];
  a.ar     = (const float *)d_in[10];
  a.av     = (const float *)d_in[11];
  a.kk     = (const float *)d_in[12];
  a.vv     = (const float *)d_in[13];
  a.rr     = (const float *)d_in[14];
  a.tf     = (const float *)d_in[15];
  a.td     = (const float *)d_in[16];
  a.ovv    = (const float *)d_in[17];
  a.tmk    = (const float *)d_in[18];
  a.tmr    = (const float *)d_in[19];
  a.kf     = (const float *)d_in[20];
  a.rf     = (const float *)d_in[21];
  a.vf     = (const float *)d_in[22];
  a.post0  = (const float *)d_in[23];
  a.post1  = (const float *)d_in[24];
  a.post2  = (const float *)d_in[25];
  a.token  = (const int *)d_in[26];
  a.out    = (float *)d_out;

  a.flags = (u32 *)d_ws;                          // 256 × 128 B = 32 KB
  float *base = (float *)((char *)d_ws + 32768);
  a.wu  = base;          // 1024
  a.wsx = base + 1024;   // 1024
  a.wx  = base + 2048;   // 1024
  a.wkm = base + 3072;   // 4096

  hipMemsetAsync(d_ws, 0, 32768, stream);
  rwkv_fused<<<NBLK, NTHR, 0, stream>>>(a);
}